// Round 3
// baseline (145.735 us; speedup 1.0000x reference)
//
#include <hip/hip_runtime.h>

#define EPSLN 1e-5f
#define KMINC 9
#define NBLK  4          // j-split blocks per (b,i)

__device__ __forceinline__ float wred64(float v){
  #pragma unroll
  for (int m=1;m<64;m<<=1) v += __shfl_xor(v,m,64);
  return v;
}
__device__ __forceinline__ float wred32(float v){
  #pragma unroll
  for (int m=1;m<32;m<<=1) v += __shfl_xor(v,m,64);
  return v;
}

// ---------------- Kernel P: fused msa-LN/attention/node  +  distance/top-k/mask ----------------
// grid = B*L (512), block = 256 (4 waves)
__global__ __launch_bounds__(256) void k_prep(
    const float* __restrict__ msa, const float* __restrict__ seq1hot,
    const float* __restrict__ xyz, const int* __restrict__ idxp,
    const int* __restrict__ topk,
    const float* __restrict__ g_msa, const float* __restrict__ b_msa,
    const float* __restrict__ Wq, const float* __restrict__ bq,
    const float* __restrict__ Wk, const float* __restrict__ bk,
    const float* __restrict__ Wx, const float* __restrict__ bx,
    const float* __restrict__ g_node, const float* __restrict__ b_node,
    float* __restrict__ node, int* __restrict__ cnt, int* __restrict__ jlist)
{
  const int bid = blockIdx.x;          // b*256 + l  (l == i)
  const int b = bid >> 8;
  const int tid = threadIdx.x;
  const int w = tid >> 6, lane = tid & 63;

  __shared__ float mn[32][64];
  __shared__ float qS[64];
  __shared__ float scS[32];
  __shared__ float redS[4][64];
  __shared__ float ssumS[4];
  __shared__ float Dv[256];
  __shared__ int   wsum[4];

  const float gm = g_msa[lane], bm = b_msa[lane];
  for (int nn=w; nn<32; nn+=4){
    float x = msa[(size_t)(((b*32+nn)<<8)+(bid&255))*64 + lane];
    float s = wred64(x), s2 = wred64(x*x);
    float mu = s*(1.f/64.f);
    float var = s2*(1.f/64.f) - mu*mu;
    mn[nn][lane] = (x-mu)*rsqrtf(var+EPSLN)*gm + bm;
  }
  __syncthreads();
  if (w==0){
    float q = bq[lane];
    for (int d=0; d<64; d++) q += mn[0][d]*Wq[d*64+lane];
    qS[lane] = q*0.125f;               // 1/sqrt(64)
  }
  __syncthreads();
  {
    float partial = 0.f;
    for (int e=w*16; e<w*16+16; e++) partial += Wk[lane*64+e]*qS[e];
    redS[w][lane] = partial;
  }
  __syncthreads();
  const float qk = redS[0][lane]+redS[1][lane]+redS[2][lane]+redS[3][lane];
  const float qb = wred64(qS[lane]*bk[lane]);
  for (int nn=w*8; nn<w*8+8; nn++){
    float p = wred64(mn[nn][lane]*qk);
    if (lane==0) scS[nn] = p + qb;
  }
  __syncthreads();
  float mx = -1e30f;
  for (int nn=0; nn<32; nn++) mx = fmaxf(mx, scS[nn]);
  float ps=0.f, pm=0.f;
  for (int nn=w*8; nn<w*8+8; nn++){
    float e = expf(scS[nn]-mx);
    ps += e; pm += e*mn[nn][lane];
  }
  redS[w][lane] = pm;
  if (lane==0) ssumS[w] = ps;
  __syncthreads();
  if (w==0){
    float ssum = ssumS[0]+ssumS[1]+ssumS[2]+ssumS[3];
    qS[lane] = (redS[0][lane]+redS[1][lane]+redS[2][lane]+redS[3][lane]) / ssum;
  }
  __syncthreads();
  if (tid<32){
    float acc = bx[tid];
    for (int k=0;k<64;k++) acc += qS[k]*Wx[k*32+tid];
    const float* s1 = &seq1hot[bid*21];
    for (int k=0;k<21;k++) acc += s1[k]*Wx[(64+k)*32+tid];
    float s = wred32(acc), s2 = wred32(acc*acc);
    float mu = s*(1.f/32.f), var = s2*(1.f/32.f)-mu*mu;
    node[bid*32+tid] = (acc-mu)*rsqrtf(var+EPSLN)*g_node[tid] + b_node[tid];
  }

  // --- Phase 2: distances, exact stable top-k rank, compaction (thread = j) ---
  const int i = bid & 255;
  const int j = tid;
  const float cax = xyz[(bid*3+1)*3+0];
  const float cay = xyz[(bid*3+1)*3+1];
  const float caz = xyz[(bid*3+1)*3+2];
  const int jb = (b<<8)+j;
  float dx = xyz[(jb*3+1)*3+0]-cax;
  float dy = xyz[(jb*3+1)*3+1]-cay;
  float dz = xyz[(jb*3+1)*3+2]-caz;
  float D = sqrtf(dx*dx+dy*dy+dz*dz) + (i==j ? 999.9f : 0.f);
  __syncthreads();
  Dv[j] = D;
  __syncthreads();
  int rank = 0;
  for (int j2=0;j2<256;j2++){
    float v = Dv[j2];
    rank += (v < D || (v == D && j2 < j)) ? 1 : 0;
  }
  int K = topk[0];
  if (K<=0 || K>256){
    float f = ((const float*)topk)[0];
    K = (f>=1.f && f<=256.f) ? (int)f : 64;
  }
  const int sep = abs(idxp[jb] - idxp[bid]);
  const bool m = (rank < K) || (i!=j && sep < KMINC);
  unsigned long long bal = __ballot(m);
  const int l6 = j & 63, wv = j >> 6;
  const int pre = __popcll(bal & ((1ull<<l6)-1ull));
  if (l6==0) wsum[wv] = __popcll(bal);
  __syncthreads();
  int off = 0;
  for (int w2=0;w2<wv;w2++) off += wsum[w2];
  if (m) jlist[bid*256 + off + pre] = j;
  if (j==0) cnt[bid] = wsum[0]+wsum[1]+wsum[2]+wsum[3];
}

// ---------------- Kernel C: gathered pair pipeline, j-split over NBLK blocks ----------------
// grid = B*L*NBLK (2048), block = 256 = 8 groups of 32; group does 4 j per pass
// Weights read directly from global (L1/L2-resident, 28 KB total). LDS ~31.5 KB.
__global__ __launch_bounds__(256) void k_main(
    const float* __restrict__ pair, const float* __restrict__ xyz,
    const float* __restrict__ g_pair, const float* __restrict__ b_pair,
    const float* __restrict__ We, const float* __restrict__ be,
    const float* __restrict__ g_edge, const float* __restrict__ b_edge,
    const float* __restrict__ Wa, const float* __restrict__ ba,
    const float* __restrict__ W0, const float* __restrict__ b0,
    const float* __restrict__ Wc1, const float* __restrict__ Wc2,
    const float* __restrict__ node, const int* __restrict__ cnt,
    const int* __restrict__ jlist, float* __restrict__ part)
{
  const int bid = blockIdx.x >> 2;     // (b,i)
  const int blk = blockIdx.x & (NBLK-1);
  const int b = bid >> 8;
  const int tid = threadIdx.x;
  const int r = tid >> 5, t = tid & 31;   // 8 groups of 32

  __shared__ float ndI[32];
  __shared__ float pnS[32*128];
  __shared__ float edS[32*32];
  __shared__ float aS[32*32];
  __shared__ float ndS[32*32];
  __shared__ float cS[32*12];
  __shared__ float xjS[32][9];
  __shared__ float redS[8][16];
  __shared__ float redO[8][9];

  if (tid<32) ndI[tid]=node[bid*32+tid];
  __syncthreads();

  const float cax = xyz[(bid*3+1)*3+0];
  const float cay = xyz[(bid*3+1)*3+1];
  const float caz = xyz[(bid*3+1)*3+2];
  const int n = cnt[bid];
  const int chunk = (n + NBLK - 1) >> 2;
  const int j0 = blk*chunk;
  const int jend = min(j0+chunk, n);

  // m0 base: b0 + node_i @ W0[32:64]
  float m0b = 0.f;
  if (t<16){
    m0b = b0[t];
    for (int k=0;k<32;k++) m0b += ndI[k]*W0[(32+k)*16+t];
  }
  const float gp0=g_pair[t], gp1=g_pair[t+32], gp2=g_pair[t+64], gp3=g_pair[t+96];
  const float bp0=b_pair[t], bp1=b_pair[t+32], bp2=b_pair[t+64], bp3=b_pair[t+96];
  const float beT=be[t], geT=g_edge[t], beeT=b_edge[t], baT=ba[t];
  const float waDT=Wa[32*32+t];

  float stA = 0.f;   // t<16: state partial
  float ofA = 0.f;   // t<9 : offset partial

  for (int base=j0; base<jend; base+=32){
    int jjs[4]; bool vals[4];
    float jxs[4], jys[4], jzs[4], dsts[4];
    #pragma unroll
    for (int jc=0;jc<4;jc++){
      const int slot = base + r*4 + jc;
      vals[jc] = slot < jend;
      jjs[jc] = vals[jc] ? jlist[bid*256+slot] : 0;
    }
    // pair-row LN (128) + stage pn, node_j, xyz_j
    #pragma unroll
    for (int jc=0;jc<4;jc++){
      const int row = r*4+jc;
      const float* prow = &pair[((long)bid*256 + jjs[jc])*128];
      float p0=prow[t], p1=prow[t+32], p2=prow[t+64], p3=prow[t+96];
      float s = wred32(p0+p1+p2+p3);
      float s2 = wred32(p0*p0+p1*p1+p2*p2+p3*p3);
      float mu = s*(1.f/128.f);
      float var = s2*(1.f/128.f)-mu*mu;
      float rs = rsqrtf(var+EPSLN);
      float* pd = &pnS[row*128];
      pd[t]    =(p0-mu)*rs*gp0+bp0;
      pd[t+32] =(p1-mu)*rs*gp1+bp1;
      pd[t+64] =(p2-mu)*rs*gp2+bp2;
      pd[t+96] =(p3-mu)*rs*gp3+bp3;
      const int jb=(b<<8)+jjs[jc];
      ndS[row*32+t] = node[jb*32+t];
      if (t<9) xjS[row][t] = xyz[(size_t)jb*9 + t];
      jxs[jc]=xyz[(jb*3+1)*3+0]-cax;
      jys[jc]=xyz[(jb*3+1)*3+1]-cay;
      jzs[jc]=xyz[(jb*3+1)*3+2]-caz;
      dsts[jc]=sqrtf(jxs[jc]*jxs[jc]+jys[jc]*jys[jc]+jzs[jc]*jzs[jc]);
    }
    // edge GEMV (128 -> 32), weights from global (L1), reuse across 4 j
    float ea[4]; ea[0]=ea[1]=ea[2]=ea[3]=beT;
    for (int k=0;k<128;k+=4){
      const float w0=We[k*32+t], w1=We[(k+1)*32+t], w2=We[(k+2)*32+t], w3=We[(k+3)*32+t];
      #pragma unroll
      for (int jc=0;jc<4;jc++){
        const float4 pv = *(const float4*)&pnS[(r*4+jc)*128+k];
        ea[jc] += pv.x*w0 + pv.y*w1 + pv.z*w2 + pv.w*w3;
      }
    }
    // edge LN (32)
    #pragma unroll
    for (int jc=0;jc<4;jc++){
      float acc=ea[jc];
      float s=wred32(acc), s2=wred32(acc*acc);
      float mu=s*(1.f/32.f), var=s2*(1.f/32.f)-mu*mu;
      edS[(r*4+jc)*32+t] = (acc-mu)*rsqrtf(var+EPSLN)*geT+beeT;
    }
    // a = relu([edge, dist] @ Wa + ba)
    float av[4];
    #pragma unroll
    for (int jc=0;jc<4;jc++) av[jc]=baT+dsts[jc]*waDT;
    for (int k=0;k<32;k+=4){
      const float w0=Wa[k*32+t], w1=Wa[(k+1)*32+t], w2=Wa[(k+2)*32+t], w3=Wa[(k+3)*32+t];
      #pragma unroll
      for (int jc=0;jc<4;jc++){
        const float4 ev = *(const float4*)&edS[(r*4+jc)*32+k];
        av[jc] += ev.x*w0 + ev.y*w1 + ev.z*w2 + ev.w*w3;
      }
    }
    #pragma unroll
    for (int jc=0;jc<4;jc++) aS[(r*4+jc)*32+t]=fmaxf(av[jc],0.f);
    // m0 = relu([a, node_i, node_j] @ W0 + b0)   (t<16)
    if (t<16){
      float m0a[4]={m0b,m0b,m0b,m0b};
      for (int k=0;k<32;k+=4){
        const float wa0=W0[k*16+t], wa1=W0[(k+1)*16+t], wa2=W0[(k+2)*16+t], wa3=W0[(k+3)*16+t];
        const float wn0=W0[(64+k)*16+t], wn1=W0[(64+k+1)*16+t], wn2=W0[(64+k+2)*16+t], wn3=W0[(64+k+3)*16+t];
        #pragma unroll
        for (int jc=0;jc<4;jc++){
          const float4 avv = *(const float4*)&aS[(r*4+jc)*32+k];
          const float4 nv  = *(const float4*)&ndS[(r*4+jc)*32+k];
          m0a[jc] += avv.x*wa0+avv.y*wa1+avv.z*wa2+avv.w*wa3
                   + nv.x*wn0 + nv.y*wn1 + nv.z*wn2 + nv.w*wn3;
        }
      }
      #pragma unroll
      for (int jc=0;jc<4;jc++) if (vals[jc]) stA += fmaxf(m0a[jc],0.f);
    }
    // c1 (3) and c2 (9) from a   (t<12)
    if (t<12){
      float cv[4]={0.f,0.f,0.f,0.f};
      for (int k=0;k<32;k+=4){
        #pragma unroll
        for (int kk=0;kk<4;kk++){
          const float w = (t<3) ? Wc1[(k+kk)*3+t] : Wc2[(k+kk)*9+(t-3)];
          #pragma unroll
          for (int jc=0;jc<4;jc++)
            cv[jc] += aS[(r*4+jc)*32+(k+kk)]*w;
        }
      }
      #pragma unroll
      for (int jc=0;jc<4;jc++) cS[(r*4+jc)*12+t]=cv[jc];
    }
    // offset accumulation: v_msg[o][x] = c1[o]*dhat[x] + sum_c c2[o][c]*l1[j][c][x]   (t<9)
    if (t<9){
      const int o=t/3, x=t-o*3;
      #pragma unroll
      for (int jc=0;jc<4;jc++){
        if (!vals[jc]) continue;
        const int row=r*4+jc;
        const float comp = (x==0)?jxs[jc]:((x==1)?jys[jc]:jzs[jc]);
        const float dh = comp/(dsts[jc]+1e-8f);
        const float* cr = &cS[row*12];
        float val = cr[o]*dh;
        const float caxj = xjS[row][3+x];
        #pragma unroll
        for (int c=0;c<3;c++){
          val += cr[3+o*3+c]*(xjS[row][c*3+x]-caxj);
        }
        ofA += val;
      }
    }
  }

  if (t<16) redS[r][t]=stA;
  if (t<9)  redO[r][t]=ofA;
  __syncthreads();
  const int pbase = (bid*NBLK+blk)*28;
  if (tid<16){
    float s=0.f;
    for (int r2=0;r2<8;r2++) s+=redS[r2][tid];
    part[pbase + tid] = s;
  }
  if (tid>=32 && tid<41){
    float s=0.f;
    for (int r2=0;r2<8;r2++) s+=redO[r2][tid-32];
    part[pbase + 16 + (tid-32)] = s;
  }
}

// ---------------- Kernel F: combine partials, scale by deg, form xyz_new ----------------
// grid = B*L (512), block = 64
__global__ __launch_bounds__(64) void k_fin(
    const float* __restrict__ xyz, const int* __restrict__ cnt,
    const float* __restrict__ part, float* __restrict__ out)
{
  const int bid = blockIdx.x;
  const int t = threadIdx.x;
  __shared__ float offF[9];
  const int n = cnt[bid];
  const float invd = 1.f/fmaxf((float)n,1.f);
  if (t<16){
    float s=0.f;
    #pragma unroll
    for (int k2=0;k2<NBLK;k2++) s += part[(bid*NBLK+k2)*28 + t];
    out[4608 + bid*16 + t] = s*invd;           // state
  } else if (t<25){
    float s=0.f;
    #pragma unroll
    for (int k2=0;k2<NBLK;k2++) s += part[(bid*NBLK+k2)*28 + t];
    offF[t-16] = s*invd;
  }
  __syncthreads();
  if (t<9){
    const int o=t/3, x=t-o*3;
    const float cac = xyz[(bid*3+1)*3+x];
    const float CA = cac + offF[3+x];          // offset[:,:,1]
    const float v = (o==1)? CA : (CA + offF[o*3+x]);
    out[bid*9 + t] = v;                        // xyz_new
  }
}

extern "C" void kernel_launch(void* const* d_in, const int* in_sizes, int n_in,
                              void* d_out, int out_size, void* d_ws, size_t ws_size,
                              hipStream_t stream)
{
  const float* msa     = (const float*)d_in[0];
  const float* pair    = (const float*)d_in[1];
  const float* xyz     = (const float*)d_in[2];
  const float* seq1hot = (const float*)d_in[3];
  const float* g_msa   = (const float*)d_in[4];
  const float* b_msa   = (const float*)d_in[5];
  const float* g_pair  = (const float*)d_in[6];
  const float* b_pair  = (const float*)d_in[7];
  const float* Wq      = (const float*)d_in[8];
  const float* bq      = (const float*)d_in[9];
  const float* Wk      = (const float*)d_in[10];
  const float* bk      = (const float*)d_in[11];
  const float* Wx      = (const float*)d_in[12];
  const float* bx      = (const float*)d_in[13];
  const float* g_node  = (const float*)d_in[14];
  const float* b_node  = (const float*)d_in[15];
  const float* We      = (const float*)d_in[16];
  const float* be      = (const float*)d_in[17];
  const float* g_edge  = (const float*)d_in[18];
  const float* b_edge  = (const float*)d_in[19];
  const float* Wa      = (const float*)d_in[20];
  const float* ba      = (const float*)d_in[21];
  const float* W0      = (const float*)d_in[22];
  const float* b0      = (const float*)d_in[23];
  const float* Wc1     = (const float*)d_in[24];
  const float* Wc2     = (const float*)d_in[25];
  const int*   idx     = (const int*)d_in[26];
  const int*   topk    = (const int*)d_in[27];
  float* out = (float*)d_out;

  float* node = (float*)d_ws;                     // 16384 f32
  int* cnt    = (int*)((char*)d_ws + 16384*4);    // 512 i32
  int* jlist  = cnt + 512;                        // 131072 i32
  float* part = (float*)(jlist + 131072);         // 512*NBLK*28 f32

  k_prep<<<512, 256, 0, stream>>>(msa, seq1hot, xyz, idx, topk, g_msa, b_msa,
                                  Wq, bq, Wk, bk, Wx, bx, g_node, b_node,
                                  node, cnt, jlist);
  k_main<<<512*NBLK, 256, 0, stream>>>(pair, xyz, g_pair, b_pair, We, be, g_edge, b_edge,
                                       Wa, ba, W0, b0, Wc1, Wc2, node, cnt, jlist, part);
  k_fin<<<512, 64, 0, stream>>>(xyz, cnt, part, out);
}

// Round 4
// 62.377 us; speedup vs baseline: 2.3364x; 2.3364x over previous
//
#include <hip/hip_runtime.h>

#define EPSLN 1e-5f
#define KMINC 9
#define NBLK  2          // j-split blocks per (b,i)

typedef _Float16 h2 __attribute__((ext_vector_type(2)));
typedef _Float16 h4 __attribute__((ext_vector_type(4)));

#if defined(__has_builtin)
#if __has_builtin(__builtin_amdgcn_fdot2)
#define FDOT2(a,b,c) __builtin_amdgcn_fdot2((a),(b),(c),false)
#endif
#endif
#ifndef FDOT2
#define FDOT2(a,b,c) ((c) + (float)(a)[0]*(float)(b)[0] + (float)(a)[1]*(float)(b)[1])
#endif

__device__ __forceinline__ h2 mk2(float a, float b){
  h2 v; v[0]=(_Float16)a; v[1]=(_Float16)b; return v;
}

__device__ __forceinline__ float wred64(float v){
  #pragma unroll
  for (int m=1;m<64;m<<=1) v += __shfl_xor(v,m,64);
  return v;
}
__device__ __forceinline__ float wred32(float v){
  #pragma unroll
  for (int m=1;m<32;m<<=1) v += __shfl_xor(v,m,64);
  return v;
}

// ---------------- Kernel P: fused msa-LN/attention/node  +  distance/top-k/mask ----------------
// grid = B*L (512), block = 256 (4 waves)
__global__ __launch_bounds__(256) void k_prep(
    const float* __restrict__ msa, const float* __restrict__ seq1hot,
    const float* __restrict__ xyz, const int* __restrict__ idxp,
    const int* __restrict__ topk,
    const float* __restrict__ g_msa, const float* __restrict__ b_msa,
    const float* __restrict__ Wq, const float* __restrict__ bq,
    const float* __restrict__ Wk, const float* __restrict__ bk,
    const float* __restrict__ Wx, const float* __restrict__ bx,
    const float* __restrict__ g_node, const float* __restrict__ b_node,
    float* __restrict__ node, int* __restrict__ cnt, int* __restrict__ jlist)
{
  const int bid = blockIdx.x;          // b*256 + l  (l == i)
  const int b = bid >> 8;
  const int tid = threadIdx.x;
  const int w = tid >> 6, lane = tid & 63;

  __shared__ float mn[32][64];
  __shared__ float qS[64];
  __shared__ float scS[32];
  __shared__ float redS[4][64];
  __shared__ float ssumS[4];
  __shared__ float Dv[256];
  __shared__ int   wsum[4];

  const float gm = g_msa[lane], bm = b_msa[lane];
  for (int nn=w; nn<32; nn+=4){
    float x = msa[(size_t)(((b*32+nn)<<8)+(bid&255))*64 + lane];
    float s = wred64(x), s2 = wred64(x*x);
    float mu = s*(1.f/64.f);
    float var = s2*(1.f/64.f) - mu*mu;
    mn[nn][lane] = (x-mu)*rsqrtf(var+EPSLN)*gm + bm;
  }
  __syncthreads();
  if (w==0){
    float q = bq[lane];
    for (int d=0; d<64; d++) q += mn[0][d]*Wq[d*64+lane];
    qS[lane] = q*0.125f;               // 1/sqrt(64)
  }
  __syncthreads();
  {
    float partial = 0.f;
    for (int e=w*16; e<w*16+16; e++) partial += Wk[lane*64+e]*qS[e];
    redS[w][lane] = partial;
  }
  __syncthreads();
  const float qk = redS[0][lane]+redS[1][lane]+redS[2][lane]+redS[3][lane];
  const float qb = wred64(qS[lane]*bk[lane]);
  for (int nn=w*8; nn<w*8+8; nn++){
    float p = wred64(mn[nn][lane]*qk);
    if (lane==0) scS[nn] = p + qb;
  }
  __syncthreads();
  float mx = -1e30f;
  for (int nn=0; nn<32; nn++) mx = fmaxf(mx, scS[nn]);
  float ps=0.f, pm=0.f;
  for (int nn=w*8; nn<w*8+8; nn++){
    float e = expf(scS[nn]-mx);
    ps += e; pm += e*mn[nn][lane];
  }
  redS[w][lane] = pm;
  if (lane==0) ssumS[w] = ps;
  __syncthreads();
  if (w==0){
    float ssum = ssumS[0]+ssumS[1]+ssumS[2]+ssumS[3];
    qS[lane] = (redS[0][lane]+redS[1][lane]+redS[2][lane]+redS[3][lane]) / ssum;
  }
  __syncthreads();
  if (tid<32){
    float acc = bx[tid];
    for (int k=0;k<64;k++) acc += qS[k]*Wx[k*32+tid];
    const float* s1 = &seq1hot[bid*21];
    for (int k=0;k<21;k++) acc += s1[k]*Wx[(64+k)*32+tid];
    float s = wred32(acc), s2 = wred32(acc*acc);
    float mu = s*(1.f/32.f), var = s2*(1.f/32.f)-mu*mu;
    node[bid*32+tid] = (acc-mu)*rsqrtf(var+EPSLN)*g_node[tid] + b_node[tid];
  }

  // --- Phase 2: distances, exact stable top-k rank, compaction (thread = j) ---
  const int i = bid & 255;
  const int j = tid;
  const float cax = xyz[(bid*3+1)*3+0];
  const float cay = xyz[(bid*3+1)*3+1];
  const float caz = xyz[(bid*3+1)*3+2];
  const int jb = (b<<8)+j;
  float dx = xyz[(jb*3+1)*3+0]-cax;
  float dy = xyz[(jb*3+1)*3+1]-cay;
  float dz = xyz[(jb*3+1)*3+2]-caz;
  float D = sqrtf(dx*dx+dy*dy+dz*dz) + (i==j ? 999.9f : 0.f);
  __syncthreads();
  Dv[j] = D;
  __syncthreads();
  int rank = 0;
  for (int j2=0;j2<256;j2++){
    float v = Dv[j2];
    rank += (v < D || (v == D && j2 < j)) ? 1 : 0;
  }
  int K = topk[0];
  if (K<=0 || K>256){
    float f = ((const float*)topk)[0];
    K = (f>=1.f && f<=256.f) ? (int)f : 64;
  }
  const int sep = abs(idxp[jb] - idxp[bid]);
  const bool m = (rank < K) || (i!=j && sep < KMINC);
  unsigned long long bal = __ballot(m);
  const int l6 = j & 63, wv = j >> 6;
  const int pre = __popcll(bal & ((1ull<<l6)-1ull));
  if (l6==0) wsum[wv] = __popcll(bal);
  __syncthreads();
  int off = 0;
  for (int w2=0;w2<wv;w2++) off += wsum[w2];
  if (m) jlist[bid*256 + off + pre] = j;
  if (j==0) cnt[bid] = wsum[0]+wsum[1]+wsum[2]+wsum[3];
}

// ---------------- Kernel C: gathered pair pipeline, f16 LDS + fdot2 ----------------
// grid = B*L*NBLK (1024), block = 256 = 8 groups of 32; group does 2 j per pass (16 rows)
// Weights packed h2 in LDS (~13.9 KB), staged activations f16. LDS total ~23.1 KB.
__global__ __launch_bounds__(256,4) void k_main(
    const float* __restrict__ pair, const float* __restrict__ xyz,
    const float* __restrict__ g_pair, const float* __restrict__ b_pair,
    const float* __restrict__ We, const float* __restrict__ be,
    const float* __restrict__ g_edge, const float* __restrict__ b_edge,
    const float* __restrict__ Wa, const float* __restrict__ ba,
    const float* __restrict__ W0, const float* __restrict__ b0,
    const float* __restrict__ Wc1, const float* __restrict__ Wc2,
    const float* __restrict__ node, const int* __restrict__ cnt,
    const int* __restrict__ jlist, float* __restrict__ part)
{
  const int bid = blockIdx.x >> 1;     // (b,i)
  const int blk = blockIdx.x & 1;
  const int b = bid >> 8;
  const int tid = threadIdx.x;
  const int r = tid >> 5, t = tid & 31;   // 8 groups of 32

  __shared__ h2 WeP[64*32];            // pairs (2q,2q+1) of We rows, col t   8 KB
  __shared__ h2 WaP[16*32];            // pairs of Wa rows 0..31              2 KB
  __shared__ float waD[32];            // Wa row 32 (dist)
  __shared__ h2 W0P[48*16];            // pairs of W0 rows 0..95              3 KB
  __shared__ h2 WcP[16*12];            // pairs of Wc rows                    768 B
  __shared__ float ndI[32];
  __shared__ alignas(16) _Float16 pnH[16][128];   // 4 KB
  __shared__ alignas(16) _Float16 edH[16][32];    // 1 KB
  __shared__ alignas(16) _Float16 aH [16][32];    // 1 KB
  __shared__ alignas(16) _Float16 ndH[16][32];    // 1 KB
  __shared__ float cS[16*12];
  __shared__ float xjS[16][9];
  __shared__ float redS[8][16];
  __shared__ float redO[8][9];

  // ---- pack weights to f16 pairs (one-time) ----
  for (int idx=tid; idx<64*32; idx+=256){
    int q=idx>>5, c=idx&31;
    WeP[idx] = mk2(We[(2*q)*32+c], We[(2*q+1)*32+c]);
  }
  for (int idx=tid; idx<16*32; idx+=256){
    int q=idx>>5, c=idx&31;
    WaP[idx] = mk2(Wa[(2*q)*32+c], Wa[(2*q+1)*32+c]);
  }
  if (tid<32) waD[tid] = Wa[32*32+tid];
  for (int idx=tid; idx<48*16; idx+=256){
    int q=idx>>4, c=idx&15;
    W0P[idx] = mk2(W0[(2*q)*16+c], W0[(2*q+1)*16+c]);
  }
  for (int idx=tid; idx<16*12; idx+=256){
    int q=idx/12, c=idx-q*12;
    float lo = (c<3)? Wc1[(2*q)*3+c]   : Wc2[(2*q)*9+(c-3)];
    float hi = (c<3)? Wc1[(2*q+1)*3+c] : Wc2[(2*q+1)*9+(c-3)];
    WcP[idx] = mk2(lo, hi);
  }
  if (tid<32) ndI[tid]=node[bid*32+tid];
  __syncthreads();

  const float cax = xyz[(bid*3+1)*3+0];
  const float cay = xyz[(bid*3+1)*3+1];
  const float caz = xyz[(bid*3+1)*3+2];
  const int n = cnt[bid];
  const int chunk = (n + 1) >> 1;
  const int j0 = blk*chunk;
  const int jend = min(j0+chunk, n);

  // m0 base: b0 + node_i @ W0[32:64]  (one-time, fp32 from global)
  float m0b = 0.f;
  if (t<16){
    m0b = b0[t];
    for (int k=0;k<32;k++) m0b += ndI[k]*W0[(32+k)*16+t];
  }
  const float4 gp4 = *(const float4*)&g_pair[4*t];
  const float4 bp4 = *(const float4*)&b_pair[4*t];
  const float beT=be[t], geT=g_edge[t], beeT=b_edge[t], baT=ba[t];
  const float waDT=waD[t];

  float stA = 0.f;   // t<16: state partial
  float ofA = 0.f;   // t<9 : offset partial

  for (int base=j0; base<jend; base+=16){
    int jjs[2]; bool vals[2];
    float jxs[2], jys[2], jzs[2], dsts[2];
    #pragma unroll
    for (int jc=0;jc<2;jc++){
      const int slot = base + r*2 + jc;
      vals[jc] = slot < jend;
      jjs[jc] = vals[jc] ? jlist[bid*256+slot] : 0;
    }
    // ---- stage: pair-row LN -> pnH (f16), node_j -> ndH, xyz_j ----
    #pragma unroll
    for (int jc=0;jc<2;jc++){
      const int row = r*2+jc;
      const float* prow = &pair[((long)bid*256 + jjs[jc])*128];
      const float4 pv4 = *(const float4*)&prow[4*t];   // lane t owns k=4t..4t+3
      float s  = wred32(pv4.x+pv4.y+pv4.z+pv4.w);
      float s2 = wred32(pv4.x*pv4.x+pv4.y*pv4.y+pv4.z*pv4.z+pv4.w*pv4.w);
      float mu = s*(1.f/128.f);
      float var = s2*(1.f/128.f)-mu*mu;
      float rs = rsqrtf(var+EPSLN);
      h4 o;
      o[0]=(_Float16)((pv4.x-mu)*rs*gp4.x+bp4.x);
      o[1]=(_Float16)((pv4.y-mu)*rs*gp4.y+bp4.y);
      o[2]=(_Float16)((pv4.z-mu)*rs*gp4.z+bp4.z);
      o[3]=(_Float16)((pv4.w-mu)*rs*gp4.w+bp4.w);
      *(h4*)&pnH[row][4*t] = o;
      const int jb=(b<<8)+jjs[jc];
      ndH[row][t] = (_Float16)node[jb*32+t];
      if (t<9) xjS[row][t] = xyz[(size_t)jb*9 + t];
      jxs[jc]=xyz[(jb*3+1)*3+0]-cax;
      jys[jc]=xyz[(jb*3+1)*3+1]-cay;
      jzs[jc]=xyz[(jb*3+1)*3+2]-caz;
      dsts[jc]=sqrtf(jxs[jc]*jxs[jc]+jys[jc]*jys[jc]+jzs[jc]*jzs[jc]);
    }
    // ---- edge GEMV (128->32) via fdot2, weights shared across 2 j ----
    float ea0[2], ea1[2];
    ea0[0]=ea0[1]=beT; ea1[0]=ea1[1]=0.f;
    for (int q=0; q<64; q+=4){
      const h2 w0=WeP[(q+0)*32+t], w1=WeP[(q+1)*32+t], w2=WeP[(q+2)*32+t], w3=WeP[(q+3)*32+t];
      #pragma unroll
      for (int jc=0;jc<2;jc++){
        const h2* pr = (const h2*)&pnH[r*2+jc][0];
        ea0[jc]=FDOT2(w1, pr[q+1], FDOT2(w0, pr[q+0], ea0[jc]));
        ea1[jc]=FDOT2(w3, pr[q+3], FDOT2(w2, pr[q+2], ea1[jc]));
      }
    }
    // ---- edge LN (32) -> edH (f16) ----
    #pragma unroll
    for (int jc=0;jc<2;jc++){
      float acc=ea0[jc]+ea1[jc];
      float s=wred32(acc), s2=wred32(acc*acc);
      float mu=s*(1.f/32.f), var=s2*(1.f/32.f)-mu*mu;
      edH[(r*2+jc)*32/32][0] = edH[0][0]; // no-op to keep layout obvious (removed by compiler)
      edH[r*2+jc][t] = (_Float16)((acc-mu)*rsqrtf(var+EPSLN)*geT+beeT);
    }
    // ---- a = relu([edge, dist] @ Wa + ba) -> aH (f16) ----
    float av[2];
    #pragma unroll
    for (int jc=0;jc<2;jc++) av[jc]=baT+dsts[jc]*waDT;
    for (int q=0; q<16; q+=4){
      const h2 w0=WaP[(q+0)*32+t], w1=WaP[(q+1)*32+t], w2=WaP[(q+2)*32+t], w3=WaP[(q+3)*32+t];
      #pragma unroll
      for (int jc=0;jc<2;jc++){
        const h2* ev = (const h2*)&edH[r*2+jc][0];
        av[jc]=FDOT2(w3, ev[q+3], FDOT2(w2, ev[q+2], FDOT2(w1, ev[q+1], FDOT2(w0, ev[q+0], av[jc]))));
      }
    }
    #pragma unroll
    for (int jc=0;jc<2;jc++) aH[r*2+jc][t]=(_Float16)fmaxf(av[jc],0.f);
    // ---- m0: a-part on lanes t<16, node_j-part on lanes t>=16, combine via shfl ----
    {
      const int half = t>>4, tc = t&15;
      const int qoff = half ? 32 : 0;      // W0 rows 64..95 for node_j part
      float m0v[2];
      m0v[0] = m0v[1] = half ? 0.f : m0b;
      for (int q=0;q<16;q+=4){
        const h2 w0=W0P[(qoff+q+0)*16+tc], w1=W0P[(qoff+q+1)*16+tc],
                 w2=W0P[(qoff+q+2)*16+tc], w3=W0P[(qoff+q+3)*16+tc];
        #pragma unroll
        for (int jc=0;jc<2;jc++){
          const _Float16* opb = half ? &ndH[r*2+jc][0] : &aH[r*2+jc][0];
          const h2* ov = (const h2*)opb;
          m0v[jc]=FDOT2(w3, ov[q+3], FDOT2(w2, ov[q+2], FDOT2(w1, ov[q+1], FDOT2(w0, ov[q+0], m0v[jc]))));
        }
      }
      #pragma unroll
      for (int jc=0;jc<2;jc++){
        float tot = m0v[jc] + __shfl_xor(m0v[jc], 16);
        if (t<16 && vals[jc]) stA += fmaxf(tot, 0.f);
      }
    }
    // ---- c1/c2 from a: lanes t<12 pairs 0..7, lanes 12..23 pairs 8..15 ----
    {
      const bool up = (t>=12 && t<24);
      const int tc12 = up ? t-12 : (t<12 ? t : 0);
      const int qb = up ? 8 : 0;
      float cv[2]={0.f,0.f};
      for (int q=0;q<8;q+=4){
        const h2 w0=WcP[(qb+q+0)*12+tc12], w1=WcP[(qb+q+1)*12+tc12],
                 w2=WcP[(qb+q+2)*12+tc12], w3=WcP[(qb+q+3)*12+tc12];
        #pragma unroll
        for (int jc=0;jc<2;jc++){
          const h2* av2 = (const h2*)&aH[r*2+jc][0];
          cv[jc]=FDOT2(w3, av2[qb+q+3], FDOT2(w2, av2[qb+q+2], FDOT2(w1, av2[qb+q+1], FDOT2(w0, av2[qb+q+0], cv[jc]))));
        }
      }
      #pragma unroll
      for (int jc=0;jc<2;jc++){
        const int src = (t<12) ? t+12 : (up ? t-12 : t);
        float other = __shfl(cv[jc], src, 32);
        if (t<12) cS[(r*2+jc)*12+t] = cv[jc]+other;
      }
    }
    // ---- offset accumulation (t<9) ----
    if (t<9){
      const int o=t/3, x=t-o*3;
      #pragma unroll
      for (int jc=0;jc<2;jc++){
        if (!vals[jc]) continue;
        const int row=r*2+jc;
        const float comp = (x==0)?jxs[jc]:((x==1)?jys[jc]:jzs[jc]);
        const float dh = comp/(dsts[jc]+1e-8f);
        const float* cr = &cS[row*12];
        float val = cr[o]*dh;
        const float caxj = xjS[row][3+x];
        #pragma unroll
        for (int c=0;c<3;c++){
          val += cr[3+o*3+c]*(xjS[row][c*3+x]-caxj);
        }
        ofA += val;
      }
    }
  }

  if (t<16) redS[r][t]=stA;
  if (t<9)  redO[r][t]=ofA;
  __syncthreads();
  const int pbase = (bid*NBLK+blk)*28;
  if (tid<16){
    float s=0.f;
    for (int r2=0;r2<8;r2++) s+=redS[r2][tid];
    part[pbase + tid] = s;
  }
  if (tid>=32 && tid<41){
    float s=0.f;
    for (int r2=0;r2<8;r2++) s+=redO[r2][tid-32];
    part[pbase + 16 + (tid-32)] = s;
  }
}

// ---------------- Kernel F: combine partials, scale by deg, form xyz_new ----------------
// grid = B*L (512), block = 64
__global__ __launch_bounds__(64) void k_fin(
    const float* __restrict__ xyz, const int* __restrict__ cnt,
    const float* __restrict__ part, float* __restrict__ out)
{
  const int bid = blockIdx.x;
  const int t = threadIdx.x;
  __shared__ float offF[9];
  const int n = cnt[bid];
  const float invd = 1.f/fmaxf((float)n,1.f);
  if (t<16){
    float s=0.f;
    #pragma unroll
    for (int k2=0;k2<NBLK;k2++) s += part[(bid*NBLK+k2)*28 + t];
    out[4608 + bid*16 + t] = s*invd;           // state
  } else if (t<25){
    float s=0.f;
    #pragma unroll
    for (int k2=0;k2<NBLK;k2++) s += part[(bid*NBLK+k2)*28 + t];
    offF[t-16] = s*invd;
  }
  __syncthreads();
  if (t<9){
    const int o=t/3, x=t-o*3;
    const float cac = xyz[(bid*3+1)*3+x];
    const float CA = cac + offF[3+x];          // offset[:,:,1]
    const float v = (o==1)? CA : (CA + offF[o*3+x]);
    out[bid*9 + t] = v;                        // xyz_new
  }
}

extern "C" void kernel_launch(void* const* d_in, const int* in_sizes, int n_in,
                              void* d_out, int out_size, void* d_ws, size_t ws_size,
                              hipStream_t stream)
{
  const float* msa     = (const float*)d_in[0];
  const float* pair    = (const float*)d_in[1];
  const float* xyz     = (const float*)d_in[2];
  const float* seq1hot = (const float*)d_in[3];
  const float* g_msa   = (const float*)d_in[4];
  const float* b_msa   = (const float*)d_in[5];
  const float* g_pair  = (const float*)d_in[6];
  const float* b_pair  = (const float*)d_in[7];
  const float* Wq      = (const float*)d_in[8];
  const float* bq      = (const float*)d_in[9];
  const float* Wk      = (const float*)d_in[10];
  const float* bk      = (const float*)d_in[11];
  const float* Wx      = (const float*)d_in[12];
  const float* bx      = (const float*)d_in[13];
  const float* g_node  = (const float*)d_in[14];
  const float* b_node  = (const float*)d_in[15];
  const float* We      = (const float*)d_in[16];
  const float* be      = (const float*)d_in[17];
  const float* g_edge  = (const float*)d_in[18];
  const float* b_edge  = (const float*)d_in[19];
  const float* Wa      = (const float*)d_in[20];
  const float* ba      = (const float*)d_in[21];
  const float* W0      = (const float*)d_in[22];
  const float* b0      = (const float*)d_in[23];
  const float* Wc1     = (const float*)d_in[24];
  const float* Wc2     = (const float*)d_in[25];
  const int*   idx     = (const int*)d_in[26];
  const int*   topk    = (const int*)d_in[27];
  float* out = (float*)d_out;

  float* node = (float*)d_ws;                     // 16384 f32
  int* cnt    = (int*)((char*)d_ws + 16384*4);    // 512 i32
  int* jlist  = cnt + 512;                        // 131072 i32
  float* part = (float*)(jlist + 131072);         // 512*NBLK*28 f32

  k_prep<<<512, 256, 0, stream>>>(msa, seq1hot, xyz, idx, topk, g_msa, b_msa,
                                  Wq, bq, Wk, bk, Wx, bx, g_node, b_node,
                                  node, cnt, jlist);
  k_main<<<512*NBLK, 256, 0, stream>>>(pair, xyz, g_pair, b_pair, We, be, g_edge, b_edge,
                                       Wa, ba, W0, b0, Wc1, Wc2, node, cnt, jlist, part);
  k_fin<<<512, 64, 0, stream>>>(xyz, cnt, part, out);
}

// Round 5
// 58.631 us; speedup vs baseline: 2.4856x; 1.0639x over previous
//
#include <hip/hip_runtime.h>

#define EPSLN 1e-5f
#define KMINC 9
#define NBLK  2          // j-split blocks per (b,i)

typedef _Float16 h2 __attribute__((ext_vector_type(2)));
typedef _Float16 h4 __attribute__((ext_vector_type(4)));

#if defined(__has_builtin)
#if __has_builtin(__builtin_amdgcn_fdot2)
#define FDOT2(a,b,c) __builtin_amdgcn_fdot2((a),(b),(c),false)
#endif
#endif
#ifndef FDOT2
#define FDOT2(a,b,c) ((c) + (float)(a)[0]*(float)(b)[0] + (float)(a)[1]*(float)(b)[1])
#endif

__device__ __forceinline__ h2 mk2(float a, float b){
  h2 v; v[0]=(_Float16)a; v[1]=(_Float16)b; return v;
}

__device__ __forceinline__ float wred64(float v){
  #pragma unroll
  for (int m=1;m<64;m<<=1) v += __shfl_xor(v,m,64);
  return v;
}
__device__ __forceinline__ float wred32(float v){
  #pragma unroll
  for (int m=1;m<32;m<<=1) v += __shfl_xor(v,m,64);
  return v;
}

// ---------------- Kernel P: fused msa-LN/attention/node  +  distance/top-k/mask ----------------
// grid = B*L (512), block = 256 (4 waves)
__global__ __launch_bounds__(256) void k_prep(
    const float* __restrict__ msa, const float* __restrict__ seq1hot,
    const float* __restrict__ xyz, const int* __restrict__ idxp,
    const int* __restrict__ topk,
    const float* __restrict__ g_msa, const float* __restrict__ b_msa,
    const float* __restrict__ Wq, const float* __restrict__ bq,
    const float* __restrict__ Wk, const float* __restrict__ bk,
    const float* __restrict__ Wx, const float* __restrict__ bx,
    const float* __restrict__ g_node, const float* __restrict__ b_node,
    float* __restrict__ node, int* __restrict__ cnt, int* __restrict__ jlist)
{
  const int bid = blockIdx.x;          // b*256 + l  (l == i)
  const int b = bid >> 8;
  const int tid = threadIdx.x;
  const int w = tid >> 6, lane = tid & 63;

  __shared__ float mn[32][64];
  __shared__ float qS[64];
  __shared__ float scS[32];
  __shared__ float redS[4][64];
  __shared__ float ssumS[4];
  __shared__ float Dv[256];
  __shared__ int   wsum[4];

  const float gm = g_msa[lane], bm = b_msa[lane];
  for (int nn=w; nn<32; nn+=4){
    float x = msa[(size_t)(((b*32+nn)<<8)+(bid&255))*64 + lane];
    float s = wred64(x), s2 = wred64(x*x);
    float mu = s*(1.f/64.f);
    float var = s2*(1.f/64.f) - mu*mu;
    mn[nn][lane] = (x-mu)*rsqrtf(var+EPSLN)*gm + bm;
  }
  __syncthreads();
  if (w==0){
    float q = bq[lane];
    for (int d=0; d<64; d++) q += mn[0][d]*Wq[d*64+lane];
    qS[lane] = q*0.125f;               // 1/sqrt(64)
  }
  __syncthreads();
  {
    float partial = 0.f;
    for (int e=w*16; e<w*16+16; e++) partial += Wk[lane*64+e]*qS[e];
    redS[w][lane] = partial;
  }
  __syncthreads();
  const float qk = redS[0][lane]+redS[1][lane]+redS[2][lane]+redS[3][lane];
  const float qb = wred64(qS[lane]*bk[lane]);
  for (int nn=w*8; nn<w*8+8; nn++){
    float p = wred64(mn[nn][lane]*qk);
    if (lane==0) scS[nn] = p + qb;
  }
  __syncthreads();
  float mx = -1e30f;
  for (int nn=0; nn<32; nn++) mx = fmaxf(mx, scS[nn]);
  float ps=0.f, pm=0.f;
  for (int nn=w*8; nn<w*8+8; nn++){
    float e = expf(scS[nn]-mx);
    ps += e; pm += e*mn[nn][lane];
  }
  redS[w][lane] = pm;
  if (lane==0) ssumS[w] = ps;
  __syncthreads();
  if (w==0){
    float ssum = ssumS[0]+ssumS[1]+ssumS[2]+ssumS[3];
    qS[lane] = (redS[0][lane]+redS[1][lane]+redS[2][lane]+redS[3][lane]) / ssum;
  }
  __syncthreads();
  if (tid<32){
    float acc = bx[tid];
    for (int k=0;k<64;k++) acc += qS[k]*Wx[k*32+tid];
    const float* s1 = &seq1hot[bid*21];
    for (int k=0;k<21;k++) acc += s1[k]*Wx[(64+k)*32+tid];
    float s = wred32(acc), s2 = wred32(acc*acc);
    float mu = s*(1.f/32.f), var = s2*(1.f/32.f)-mu*mu;
    node[bid*32+tid] = (acc-mu)*rsqrtf(var+EPSLN)*g_node[tid] + b_node[tid];
  }

  // --- Phase 2: distances, exact stable top-k rank, compaction (thread = j) ---
  const int i = bid & 255;
  const int j = tid;
  const float cax = xyz[(bid*3+1)*3+0];
  const float cay = xyz[(bid*3+1)*3+1];
  const float caz = xyz[(bid*3+1)*3+2];
  const int jb = (b<<8)+j;
  float dx = xyz[(jb*3+1)*3+0]-cax;
  float dy = xyz[(jb*3+1)*3+1]-cay;
  float dz = xyz[(jb*3+1)*3+2]-caz;
  float D = sqrtf(dx*dx+dy*dy+dz*dz) + (i==j ? 999.9f : 0.f);
  __syncthreads();
  Dv[j] = D;
  __syncthreads();
  int rank = 0;
  for (int j2=0;j2<256;j2++){
    float v = Dv[j2];
    rank += (v < D || (v == D && j2 < j)) ? 1 : 0;
  }
  int K = topk[0];
  if (K<=0 || K>256){
    float f = ((const float*)topk)[0];
    K = (f>=1.f && f<=256.f) ? (int)f : 64;
  }
  const int sep = abs(idxp[jb] - idxp[bid]);
  const bool m = (rank < K) || (i!=j && sep < KMINC);
  unsigned long long bal = __ballot(m);
  const int l6 = j & 63, wv = j >> 6;
  const int pre = __popcll(bal & ((1ull<<l6)-1ull));
  if (l6==0) wsum[wv] = __popcll(bal);
  __syncthreads();
  int off = 0;
  for (int w2=0;w2<wv;w2++) off += wsum[w2];
  if (m) jlist[bid*256 + off + pre] = j;
  if (j==0) cnt[bid] = wsum[0]+wsum[1]+wsum[2]+wsum[3];
}

// ---------------- Kernel C: gathered pair pipeline, f16 LDS + fdot2 ----------------
// grid = B*L*NBLK (1024), block = 256 = 8 groups of 32; group does 2 j per pass (16 rows)
// Weights packed h2 in LDS (~13.9 KB); staged activations f16; per-row geometry in LDS
// (geoS) so no long-lived per-thread registers span the GEMV chain (r4 spill fix).
// amdgpu_waves_per_eu(4,4): 128-VGPR budget, stops the allocator spilling to the 64-bucket.
__global__ __launch_bounds__(256) __attribute__((amdgpu_waves_per_eu(4,4))) void k_main(
    const float* __restrict__ pair, const float* __restrict__ xyz,
    const float* __restrict__ g_pair, const float* __restrict__ b_pair,
    const float* __restrict__ We, const float* __restrict__ be,
    const float* __restrict__ g_edge, const float* __restrict__ b_edge,
    const float* __restrict__ Wa, const float* __restrict__ ba,
    const float* __restrict__ W0, const float* __restrict__ b0,
    const float* __restrict__ Wc1, const float* __restrict__ Wc2,
    const float* __restrict__ node, const int* __restrict__ cnt,
    const int* __restrict__ jlist, float* __restrict__ part)
{
  const int bid = blockIdx.x >> 1;     // (b,i)
  const int blk = blockIdx.x & 1;
  const int b = bid >> 8;
  const int tid = threadIdx.x;
  const int r = tid >> 5, t = tid & 31;   // 8 groups of 32

  __shared__ h2 WeP[64*32];            // pairs (2q,2q+1) of We rows, col t   8 KB
  __shared__ h2 WaP[16*32];            // pairs of Wa rows 0..31              2 KB
  __shared__ float waD[32];            // Wa row 32 (dist)
  __shared__ h2 W0P[48*16];            // pairs of W0 rows 0..95              3 KB
  __shared__ h2 WcP[16*12];            // pairs of Wc rows                    768 B
  __shared__ float ndI[32];
  __shared__ alignas(16) _Float16 pnH[16][128];   // 4 KB
  __shared__ alignas(16) _Float16 edH[16][32];    // 1 KB
  __shared__ alignas(16) _Float16 aH [16][32];    // 1 KB
  __shared__ alignas(16) _Float16 ndH[16][32];    // 1 KB
  __shared__ float cS[16*12];
  __shared__ float xjS[16][9];
  __shared__ float geoS[16][4];        // dx,dy,dz,dist per staged row
  __shared__ float redS[8][16];
  __shared__ float redO[8][9];

  // ---- pack weights to f16 pairs (one-time) ----
  for (int idx=tid; idx<64*32; idx+=256){
    int q=idx>>5, c=idx&31;
    WeP[idx] = mk2(We[(2*q)*32+c], We[(2*q+1)*32+c]);
  }
  for (int idx=tid; idx<16*32; idx+=256){
    int q=idx>>5, c=idx&31;
    WaP[idx] = mk2(Wa[(2*q)*32+c], Wa[(2*q+1)*32+c]);
  }
  if (tid<32) waD[tid] = Wa[32*32+tid];
  for (int idx=tid; idx<48*16; idx+=256){
    int q=idx>>4, c=idx&15;
    W0P[idx] = mk2(W0[(2*q)*16+c], W0[(2*q+1)*16+c]);
  }
  for (int idx=tid; idx<16*12; idx+=256){
    int q=idx/12, c=idx-q*12;
    float lo = (c<3)? Wc1[(2*q)*3+c]   : Wc2[(2*q)*9+(c-3)];
    float hi = (c<3)? Wc1[(2*q+1)*3+c] : Wc2[(2*q+1)*9+(c-3)];
    WcP[idx] = mk2(lo, hi);
  }
  if (tid<32) ndI[tid]=node[bid*32+tid];
  __syncthreads();

  const float cax = xyz[(bid*3+1)*3+0];
  const float cay = xyz[(bid*3+1)*3+1];
  const float caz = xyz[(bid*3+1)*3+2];
  const int n = cnt[bid];
  const int chunk = (n + 1) >> 1;
  const int j0 = blk*chunk;
  const int jend = min(j0+chunk, n);

  // m0 base: b0 + node_i @ W0[32:64]  (one-time, fp32 from global)
  float m0b = 0.f;
  if (t<16){
    m0b = b0[t];
    for (int k=0;k<32;k++) m0b += ndI[k]*W0[(32+k)*16+t];
  }
  const float beT=be[t], geT=g_edge[t], beeT=b_edge[t], baT=ba[t];
  const float waDT=waD[t];

  float stA = 0.f;   // t<16: state partial
  float ofA = 0.f;   // t<9 : offset partial

  for (int base=j0; base<jend; base+=16){
    bool vals[2];
    // ---- stage: pair-row LN -> pnH (f16), node_j -> ndH, xyz_j, geometry -> LDS ----
    {
      const float4 gp4 = *(const float4*)&g_pair[4*t];
      const float4 bp4 = *(const float4*)&b_pair[4*t];
      #pragma unroll
      for (int jc=0;jc<2;jc++){
        const int slot = base + r*2 + jc;
        vals[jc] = slot < jend;
        const int jj = vals[jc] ? jlist[bid*256+slot] : 0;
        const int row = r*2+jc;
        const float* prow = &pair[((long)bid*256 + jj)*128];
        const float4 pv4 = *(const float4*)&prow[4*t];   // lane t owns k=4t..4t+3
        float s  = wred32(pv4.x+pv4.y+pv4.z+pv4.w);
        float s2 = wred32(pv4.x*pv4.x+pv4.y*pv4.y+pv4.z*pv4.z+pv4.w*pv4.w);
        float mu = s*(1.f/128.f);
        float var = s2*(1.f/128.f)-mu*mu;
        float rs = rsqrtf(var+EPSLN);
        h4 o;
        o[0]=(_Float16)((pv4.x-mu)*rs*gp4.x+bp4.x);
        o[1]=(_Float16)((pv4.y-mu)*rs*gp4.y+bp4.y);
        o[2]=(_Float16)((pv4.z-mu)*rs*gp4.z+bp4.z);
        o[3]=(_Float16)((pv4.w-mu)*rs*gp4.w+bp4.w);
        *(h4*)&pnH[row][4*t] = o;
        const int jb=(b<<8)+jj;
        ndH[row][t] = (_Float16)node[jb*32+t];
        if (t<9) xjS[row][t] = xyz[(size_t)jb*9 + t];
        if (t==0){
          float jx = xyz[(size_t)jb*9+3]-cax;
          float jy = xyz[(size_t)jb*9+4]-cay;
          float jz = xyz[(size_t)jb*9+5]-caz;
          geoS[row][0]=jx; geoS[row][1]=jy; geoS[row][2]=jz;
          geoS[row][3]=sqrtf(jx*jx+jy*jy+jz*jz);
        }
      }
    }
    // ---- edge GEMV (128->32) via fdot2, weights shared across 2 j ----
    float ea0[2], ea1[2];
    ea0[0]=ea0[1]=beT; ea1[0]=ea1[1]=0.f;
    for (int q=0; q<64; q+=4){
      const h2 w0=WeP[(q+0)*32+t], w1=WeP[(q+1)*32+t], w2=WeP[(q+2)*32+t], w3=WeP[(q+3)*32+t];
      #pragma unroll
      for (int jc=0;jc<2;jc++){
        const h2* pr = (const h2*)&pnH[r*2+jc][0];
        ea0[jc]=FDOT2(w1, pr[q+1], FDOT2(w0, pr[q+0], ea0[jc]));
        ea1[jc]=FDOT2(w3, pr[q+3], FDOT2(w2, pr[q+2], ea1[jc]));
      }
    }
    // ---- edge LN (32) -> edH (f16) ----
    #pragma unroll
    for (int jc=0;jc<2;jc++){
      float acc=ea0[jc]+ea1[jc];
      float s=wred32(acc), s2=wred32(acc*acc);
      float mu=s*(1.f/32.f), var=s2*(1.f/32.f)-mu*mu;
      edH[r*2+jc][t] = (_Float16)((acc-mu)*rsqrtf(var+EPSLN)*geT+beeT);
    }
    // ---- a = relu([edge, dist] @ Wa + ba) -> aH (f16) ----
    float av[2];
    #pragma unroll
    for (int jc=0;jc<2;jc++) av[jc]=baT+geoS[r*2+jc][3]*waDT;
    for (int q=0; q<16; q+=4){
      const h2 w0=WaP[(q+0)*32+t], w1=WaP[(q+1)*32+t], w2=WaP[(q+2)*32+t], w3=WaP[(q+3)*32+t];
      #pragma unroll
      for (int jc=0;jc<2;jc++){
        const h2* ev = (const h2*)&edH[r*2+jc][0];
        av[jc]=FDOT2(w3, ev[q+3], FDOT2(w2, ev[q+2], FDOT2(w1, ev[q+1], FDOT2(w0, ev[q+0], av[jc]))));
      }
    }
    #pragma unroll
    for (int jc=0;jc<2;jc++) aH[r*2+jc][t]=(_Float16)fmaxf(av[jc],0.f);
    // ---- m0: a-part on lanes t<16, node_j-part on lanes t>=16, combine via shfl ----
    {
      const int half = t>>4, tc = t&15;
      const int qoff = half ? 32 : 0;      // W0 rows 64..95 for node_j part
      float m0v[2];
      m0v[0] = m0v[1] = half ? 0.f : m0b;
      for (int q=0;q<16;q+=4){
        const h2 w0=W0P[(qoff+q+0)*16+tc], w1=W0P[(qoff+q+1)*16+tc],
                 w2=W0P[(qoff+q+2)*16+tc], w3=W0P[(qoff+q+3)*16+tc];
        #pragma unroll
        for (int jc=0;jc<2;jc++){
          const _Float16* opb = half ? &ndH[r*2+jc][0] : &aH[r*2+jc][0];
          const h2* ov = (const h2*)opb;
          m0v[jc]=FDOT2(w3, ov[q+3], FDOT2(w2, ov[q+2], FDOT2(w1, ov[q+1], FDOT2(w0, ov[q+0], m0v[jc]))));
        }
      }
      #pragma unroll
      for (int jc=0;jc<2;jc++){
        float tot = m0v[jc] + __shfl_xor(m0v[jc], 16);
        if (t<16 && vals[jc]) stA += fmaxf(tot, 0.f);
      }
    }
    // ---- c1/c2 from a: lanes t<12 pairs 0..7, lanes 12..23 pairs 8..15 ----
    {
      const bool up = (t>=12 && t<24);
      const int tc12 = up ? t-12 : (t<12 ? t : 0);
      const int qb = up ? 8 : 0;
      float cv[2]={0.f,0.f};
      for (int q=0;q<8;q+=4){
        const h2 w0=WcP[(qb+q+0)*12+tc12], w1=WcP[(qb+q+1)*12+tc12],
                 w2=WcP[(qb+q+2)*12+tc12], w3=WcP[(qb+q+3)*12+tc12];
        #pragma unroll
        for (int jc=0;jc<2;jc++){
          const h2* av2 = (const h2*)&aH[r*2+jc][0];
          cv[jc]=FDOT2(w3, av2[qb+q+3], FDOT2(w2, av2[qb+q+2], FDOT2(w1, av2[qb+q+1], FDOT2(w0, av2[qb+q+0], cv[jc]))));
        }
      }
      #pragma unroll
      for (int jc=0;jc<2;jc++){
        const int src = (t<12) ? t+12 : (up ? t-12 : t);
        float other = __shfl(cv[jc], src, 32);
        if (t<12) cS[(r*2+jc)*12+t] = cv[jc]+other;
      }
    }
    // ---- offset accumulation (t<9), geometry from LDS ----
    if (t<9){
      const int o=t/3, x=t-o*3;
      #pragma unroll
      for (int jc=0;jc<2;jc++){
        if (!vals[jc]) continue;
        const int row=r*2+jc;
        const float dj = geoS[row][3];
        const float dh = geoS[row][x]/(dj+1e-8f);
        const float* cr = &cS[row*12];
        float val = cr[o]*dh;
        const float caxj = xjS[row][3+x];
        #pragma unroll
        for (int c=0;c<3;c++){
          val += cr[3+o*3+c]*(xjS[row][c*3+x]-caxj);
        }
        ofA += val;
      }
    }
  }

  if (t<16) redS[r][t]=stA;
  if (t<9)  redO[r][t]=ofA;
  __syncthreads();
  const int pbase = (bid*NBLK+blk)*28;
  if (tid<16){
    float s=0.f;
    for (int r2=0;r2<8;r2++) s+=redS[r2][tid];
    part[pbase + tid] = s;
  }
  if (tid>=32 && tid<41){
    float s=0.f;
    for (int r2=0;r2<8;r2++) s+=redO[r2][tid-32];
    part[pbase + 16 + (tid-32)] = s;
  }
}

// ---------------- Kernel F: combine partials, scale by deg, form xyz_new ----------------
// grid = B*L (512), block = 64
__global__ __launch_bounds__(64) void k_fin(
    const float* __restrict__ xyz, const int* __restrict__ cnt,
    const float* __restrict__ part, float* __restrict__ out)
{
  const int bid = blockIdx.x;
  const int t = threadIdx.x;
  __shared__ float offF[9];
  const int n = cnt[bid];
  const float invd = 1.f/fmaxf((float)n,1.f);
  if (t<16){
    float s=0.f;
    #pragma unroll
    for (int k2=0;k2<NBLK;k2++) s += part[(bid*NBLK+k2)*28 + t];
    out[4608 + bid*16 + t] = s*invd;           // state
  } else if (t<25){
    float s=0.f;
    #pragma unroll
    for (int k2=0;k2<NBLK;k2++) s += part[(bid*NBLK+k2)*28 + t];
    offF[t-16] = s*invd;
  }
  __syncthreads();
  if (t<9){
    const int o=t/3, x=t-o*3;
    const float cac = xyz[(bid*3+1)*3+x];
    const float CA = cac + offF[3+x];          // offset[:,:,1]
    const float v = (o==1)? CA : (CA + offF[o*3+x]);
    out[bid*9 + t] = v;                        // xyz_new
  }
}

extern "C" void kernel_launch(void* const* d_in, const int* in_sizes, int n_in,
                              void* d_out, int out_size, void* d_ws, size_t ws_size,
                              hipStream_t stream)
{
  const float* msa     = (const float*)d_in[0];
  const float* pair    = (const float*)d_in[1];
  const float* xyz     = (const float*)d_in[2];
  const float* seq1hot = (const float*)d_in[3];
  const float* g_msa   = (const float*)d_in[4];
  const float* b_msa   = (const float*)d_in[5];
  const float* g_pair  = (const float*)d_in[6];
  const float* b_pair  = (const float*)d_in[7];
  const float* Wq      = (const float*)d_in[8];
  const float* bq      = (const float*)d_in[9];
  const float* Wk      = (const float*)d_in[10];
  const float* bk      = (const float*)d_in[11];
  const float* Wx      = (const float*)d_in[12];
  const float* bx      = (const float*)d_in[13];
  const float* g_node  = (const float*)d_in[14];
  const float* b_node  = (const float*)d_in[15];
  const float* We      = (const float*)d_in[16];
  const float* be      = (const float*)d_in[17];
  const float* g_edge  = (const float*)d_in[18];
  const float* b_edge  = (const float*)d_in[19];
  const float* Wa      = (const float*)d_in[20];
  const float* ba      = (const float*)d_in[21];
  const float* W0      = (const float*)d_in[22];
  const float* b0      = (const float*)d_in[23];
  const float* Wc1     = (const float*)d_in[24];
  const float* Wc2     = (const float*)d_in[25];
  const int*   idx     = (const int*)d_in[26];
  const int*   topk    = (const int*)d_in[27];
  float* out = (float*)d_out;

  float* node = (float*)d_ws;                     // 16384 f32
  int* cnt    = (int*)((char*)d_ws + 16384*4);    // 512 i32
  int* jlist  = cnt + 512;                        // 131072 i32
  float* part = (float*)(jlist + 131072);         // 512*NBLK*28 f32

  k_prep<<<512, 256, 0, stream>>>(msa, seq1hot, xyz, idx, topk, g_msa, b_msa,
                                  Wq, bq, Wk, bk, Wx, bx, g_node, b_node,
                                  node, cnt, jlist);
  k_main<<<512*NBLK, 256, 0, stream>>>(pair, xyz, g_pair, b_pair, We, be, g_edge, b_edge,
                                       Wa, ba, W0, b0, Wc1, Wc2, node, cnt, jlist, part);
  k_fin<<<512, 64, 0, stream>>>(xyz, cnt, part, out);
}